// Round 6
// baseline (1820.702 us; speedup 1.0000x reference)
//
#include <hip/hip_runtime.h>
#include <hip/hip_bf16.h>
#include <cstdint>
#include <cstddef>

typedef __attribute__((ext_vector_type(4))) float f32x4;
typedef __attribute__((ext_vector_type(2))) float f32x2;
typedef __attribute__((ext_vector_type(8))) short s16x8;
typedef __attribute__((ext_vector_type(8))) unsigned short u16x8;

#define NB 32
#define DD 512
#define TT 4096
#define HH 512
#define TBG 256   // t-tile per kGemmE block
#define NKK 16    // K-steps of 32

__device__ __forceinline__ unsigned short f2bf(float f) {
  uint32_t u = __builtin_bit_cast(uint32_t, f);
  u += 0x7fffu + ((u >> 16) & 1u);   // RNE
  return (unsigned short)(u >> 16);
}

__device__ __forceinline__ float tanh_fast(float x) {
  x = fminf(fmaxf(x, -15.f), 15.f);
  float e = __expf(2.f * x);
  return (e - 1.f) / (e + 1.f);
}

// --- A1: W1swz[kk32][s][h] : 16B chunk = W1[h][kk32*32+s*8 .. +7] bf16 ---
__global__ void kConvT(const float* __restrict__ w42, u16x8* __restrict__ W1swz) {
  int g = blockIdx.x * 256 + threadIdx.x;
  int h = g & 511, sk = g >> 9;
  int kk = sk >> 2, s = sk & 3;
  const float* src = &w42[h * 1024 + kk * 32 + s * 8];
  f32x4 v0 = *reinterpret_cast<const f32x4*>(src);
  f32x4 v1 = *reinterpret_cast<const f32x4*>(src + 4);
  u16x8 c;
  c[0] = f2bf(v0.x); c[1] = f2bf(v0.y); c[2] = f2bf(v0.z); c[3] = f2bf(v0.w);
  c[4] = f2bf(v1.x); c[5] = f2bf(v1.y); c[6] = f2bf(v1.z); c[7] = f2bf(v1.w);
  W1swz[kk * 2048 + s * 512 + h] = c;
}

// --- A2: qterm[b,h] = w42[h,512:]·query[b] + b4[h] ---
__global__ void kQterm(const float* __restrict__ w42, const float* __restrict__ query,
                       const float* __restrict__ b4, float* __restrict__ qterm) {
  int wid = blockIdx.x * 4 + (threadIdx.x >> 6);
  int lane = threadIdx.x & 63;
  int b = wid >> 9, h = wid & 511;
  const float* wr = &w42[h * 1024 + 512];
  const float* q  = &query[b * 512];
  int d = lane * 8;
  f32x4 w0 = *(const f32x4*)&wr[d], w1 = *(const f32x4*)&wr[d + 4];
  f32x4 q0 = *(const f32x4*)&q[d],  q1 = *(const f32x4*)&q[d + 4];
  float s = w0.x*q0.x + w0.y*q0.y + w0.z*q0.z + w0.w*q0.w
          + w1.x*q1.x + w1.y*q1.y + w1.z*q1.z + w1.w*q1.w;
  #pragma unroll
  for (int off = 32; off; off >>= 1) s += __shfl_xor(s, off);
  if (lane == 0) qterm[b * 512 + h] = s + b4[h];
}

// --- B: GEMM + tanh + h-reduce + exp.  512 threads, 512h x 256t per block.
__global__ __launch_bounds__(512, 4) void kGemmE(
    const float* __restrict__ keys, const u16x8* __restrict__ W1swz,
    const float* __restrict__ qterm, const float* __restrict__ w54,
    float* __restrict__ e, float* __restrict__ Zp) {
  __shared__ s16x8 Bs[2][1024];     // 32 KB swizzled chunks [buf][(s*256+t)^swz]
  __shared__ float red[4][256];     // 4 KB
  __shared__ float zsh[4];

  int bid = blockIdx.x;
  int b = bid >> 4, tblk = bid & 15;
  int t0 = tblk * TBG;
  int tid = threadIdx.x, lane = tid & 63, wid = tid >> 6;
  int wh = wid & 3, wt = wid >> 2;       // h-quadrant, t-half
  int lr = lane & 15, lg = lane >> 4;

  // B staging: thread covers t = tt, tt+1 and k-rows kg*8 .. kg*8+7
  int tt = (tid & 127) * 2, kg = tid >> 7;
  const float* kp = keys + (size_t)b * DD * TT + (size_t)(kg * 8) * TT + t0 + tt;
  const s16x8* ap = reinterpret_cast<const s16x8*>(W1swz) + lg * 512 + wh * 128 + lr;

  // swizzled LDS chunk indices (precomputed, loop-invariant)
  int wsw = ((tt >> 1) ^ (kg << 1)) & 7;
  int wi0 = (kg * 256 + tt) ^ wsw;
  int wi1 = (kg * 256 + tt + 1) ^ wsw;
  int rci[8];
  #pragma unroll
  for (int n = 0; n < 8; ++n) {
    int t = wt * 128 + n * 16 + lr;
    rci[n] = (lg * 256 + t) ^ (((t >> 1) ^ (lg << 1)) & 7);
  }

  f32x4 acc[8][8];
  #pragma unroll
  for (int m = 0; m < 8; ++m)
    #pragma unroll
    for (int n = 0; n < 8; ++n) acc[m][n] = (f32x4){0.f, 0.f, 0.f, 0.f};

  f32x2 r[2][8];
  #pragma unroll
  for (int j = 0; j < 8; ++j)
    r[0][j] = __builtin_nontemporal_load(reinterpret_cast<const f32x2*>(&kp[(size_t)j * TT]));
  #pragma unroll
  for (int j = 0; j < 8; ++j)
    r[1][j] = __builtin_nontemporal_load(reinterpret_cast<const f32x2*>(&kp[(size_t)(32 + j) * TT]));

#define GSTEP(CUR, KK)                                                         \
  {                                                                            \
    s16x8 af[8];                                                               \
    _Pragma("unroll")                                                          \
    for (int m = 0; m < 8; ++m) af[m] = ap[(KK) * 2048 + m * 16];              \
    s16x8 c0, c1;                                                              \
    _Pragma("unroll")                                                          \
    for (int j = 0; j < 8; ++j) {                                              \
      c0[j] = (short)f2bf(r[CUR][j].x);                                        \
      c1[j] = (short)f2bf(r[CUR][j].y);                                        \
    }                                                                          \
    Bs[CUR][wi0] = c0;                                                         \
    Bs[CUR][wi1] = c1;                                                         \
    if ((KK) + 2 < NKK) {                                                      \
      const float* kp2 = kp + (size_t)((KK) + 2) * 32 * TT;                    \
      _Pragma("unroll")                                                        \
      for (int j = 0; j < 8; ++j)                                              \
        r[CUR][j] = __builtin_nontemporal_load(                                \
            reinterpret_cast<const f32x2*>(&kp2[(size_t)j * TT]));             \
    }                                                                          \
    asm volatile("s_waitcnt lgkmcnt(0)" ::: "memory");                         \
    __builtin_amdgcn_s_barrier();                                              \
    s16x8 bf[8];                                                               \
    _Pragma("unroll")                                                          \
    for (int n = 0; n < 8; ++n) bf[n] = Bs[CUR][rci[n]];                       \
    _Pragma("unroll")                                                          \
    for (int m = 0; m < 8; ++m)                                                \
      _Pragma("unroll")                                                        \
      for (int n = 0; n < 8; ++n)                                              \
        acc[m][n] = __builtin_amdgcn_mfma_f32_16x16x32_bf16(                   \
            af[m], bf[n], acc[m][n], 0, 0, 0);                                 \
  }

  for (int kk2 = 0; kk2 < NKK / 2; ++kk2) {
    GSTEP(0, 2 * kk2);
    GSTEP(1, 2 * kk2 + 1);
  }
#undef GSTEP

  // epilogue: tanh + w54-weighted reduce over this wave's 128 h
  float part[8] = {0.f, 0.f, 0.f, 0.f, 0.f, 0.f, 0.f, 0.f};
  #pragma unroll
  for (int m = 0; m < 8; ++m) {
    #pragma unroll
    for (int rr = 0; rr < 4; ++rr) {
      int h = wh * 128 + m * 16 + lg * 4 + rr;   // C/D: row=(lane>>4)*4+reg
      float qv = qterm[b * HH + h];
      float wvv = w54[h];
      #pragma unroll
      for (int n = 0; n < 8; ++n)
        part[n] += wvv * tanh_fast(acc[m][n][rr] + qv);
    }
  }
  #pragma unroll
  for (int n = 0; n < 8; ++n) {
    part[n] += __shfl_xor(part[n], 16);
    part[n] += __shfl_xor(part[n], 32);
  }
  if (lane < 16) {
    #pragma unroll
    for (int n = 0; n < 8; ++n) red[wh][wt * 128 + n * 16 + lane] = part[n];
  }
  __syncthreads();
  if (tid < 256) {
    float v = red[0][tid] + red[1][tid] + red[2][tid] + red[3][tid];
    float ev = __expf(v);                  // |n5| <~ 4: no max-sub needed
    e[b * TT + t0 + tid] = ev;
    float z = ev;
    #pragma unroll
    for (int off = 32; off; off >>= 1) z += __shfl_xor(z, off);
    if (lane == 0) zsh[wid] = z;
  }
  __syncthreads();
  if (tid == 0) Zp[b * 16 + tblk] = zsh[0] + zsh[1] + zsh[2] + zsh[3];
}

// --- C: Zinv[b] = 1 / sum_tiles Zp[b][tile] ---
__global__ void kZinv(const float* __restrict__ Zp, float* __restrict__ Zinv) {
  int b = blockIdx.x, lane = threadIdx.x;
  float z = lane < 16 ? Zp[b * 16 + lane] : 0.f;
  #pragma unroll
  for (int off = 8; off; off >>= 1) z += __shfl_xor(z, off);
  if (lane == 0) Zinv[b] = 1.f / z;
}

// --- D: out[b,v] = Zinv[b] * values[b,v,:]·e[b,:] ---
__global__ void kOut(const float* __restrict__ values, const float* __restrict__ e,
                     const float* __restrict__ Zinv, float* __restrict__ out) {
  int blk = blockIdx.x;
  int b = blk >> 7;
  int wid = threadIdx.x >> 6, lane = threadIdx.x & 63;
  int v = (blk & 127) * 4 + wid;
  const float* row = &values[((size_t)b * 512 + v) * TT];
  const float* wv = &e[b * TT];
  float s0 = 0.f, s1 = 0.f, s2 = 0.f, s3 = 0.f;
  #pragma unroll
  for (int i = 0; i < 16; ++i) {
    int t = (i * 64 + lane) * 4;
    f32x4 x = __builtin_nontemporal_load(reinterpret_cast<const f32x4*>(&row[t]));
    f32x4 y = *(const f32x4*)&wv[t];
    float d = x.x * y.x + x.y * y.y + x.z * y.z + x.w * y.w;
    if ((i & 3) == 0) s0 += d; else if ((i & 3) == 1) s1 += d;
    else if ((i & 3) == 2) s2 += d; else s3 += d;
  }
  float s = (s0 + s1) + (s2 + s3);
  #pragma unroll
  for (int off = 32; off; off >>= 1) s += __shfl_xor(s, off);
  if (lane == 0) out[b * 512 + v] = s * Zinv[b];
}

extern "C" void kernel_launch(void* const* d_in, const int* in_sizes, int n_in,
                              void* d_out, int out_size, void* d_ws, size_t ws_size,
                              hipStream_t stream) {
  const float* query  = (const float*)d_in[0];
  const float* keys   = (const float*)d_in[1];
  const float* values = (const float*)d_in[2];
  const float* w42    = (const float*)d_in[3];
  const float* b4     = (const float*)d_in[4];
  const float* w54    = (const float*)d_in[5];
  // d_in[6] (b5) shifts n5 by a constant -> softmax-invariant; unused.
  float* out = (float*)d_out;

  char* ws = (char*)d_ws;
  u16x8* W1swz = (u16x8*)ws;                       // 512 KB
  float* qterm = (float*)(ws + (512 << 10));       // 64 KB
  float* Zp    = (float*)(ws + (576 << 10));       // 2 KB  [B][16]
  float* Zinv  = (float*)(ws + (592 << 10));       // 128 B
  float* e     = (float*)(ws + (640 << 10));       // 512 KB [B][T]

  kConvT <<<128, 256, 0, stream>>>(w42, W1swz);
  kQterm <<<4096, 256, 0, stream>>>(w42, query, b4, qterm);
  kGemmE <<<512, 512, 0, stream>>>(keys, W1swz, qterm, w54, e, Zp);
  kZinv  <<<32, 64, 0, stream>>>(Zp, Zinv);
  kOut   <<<4096, 256, 0, stream>>>(values, e, Zinv, out);
}

// Round 7
// 184.036 us; speedup vs baseline: 9.8932x; 9.8932x over previous
//
#include <hip/hip_runtime.h>
#include <hip/hip_bf16.h>
#include <cstdint>
#include <cstddef>

typedef __attribute__((ext_vector_type(4))) float f32x4;
typedef __attribute__((ext_vector_type(8))) short s16x8;
typedef __attribute__((ext_vector_type(8))) unsigned short u16x8;

#define NB 32
#define DD 512
#define TT 4096
#define HH 512
#define NKK 16    // K-steps of 32

__device__ __forceinline__ unsigned short f2bf(float f) {
  uint32_t u = __builtin_bit_cast(uint32_t, f);
  u += 0x7fffu + ((u >> 16) & 1u);   // RNE
  return (unsigned short)(u >> 16);
}

__device__ __forceinline__ uint32_t cvtpk(float a, float b) {
  uint32_t d;
  asm("v_cvt_pk_bf16_f32 %0, %1, %2" : "=v"(d) : "v"(a), "v"(b));
  return d;   // low16 = bf16(a), high16 = bf16(b)
}

__device__ __forceinline__ float tanh_fast(float x) {
  x = fminf(fmaxf(x, -15.f), 15.f);
  float e = __expf(2.f * x);
  return (e - 1.f) / (e + 1.f);
}

// --- A1: W1swz[kk32][s][h] : 16B chunk = W1[h][kk32*32+s*8 .. +7] bf16 ---
__global__ void kConvT(const float* __restrict__ w42, u16x8* __restrict__ W1swz) {
  int g = blockIdx.x * 256 + threadIdx.x;
  int h = g & 511, sk = g >> 9;
  int kk = sk >> 2, s = sk & 3;
  const float* src = &w42[h * 1024 + kk * 32 + s * 8];
  f32x4 v0 = *reinterpret_cast<const f32x4*>(src);
  f32x4 v1 = *reinterpret_cast<const f32x4*>(src + 4);
  u16x8 c;
  c[0] = f2bf(v0.x); c[1] = f2bf(v0.y); c[2] = f2bf(v0.z); c[3] = f2bf(v0.w);
  c[4] = f2bf(v1.x); c[5] = f2bf(v1.y); c[6] = f2bf(v1.z); c[7] = f2bf(v1.w);
  W1swz[kk * 2048 + s * 512 + h] = c;
}

// --- A2: qterm[b,h] = w42[h,512:]·query[b] + b4[h] ---
__global__ void kQterm(const float* __restrict__ w42, const float* __restrict__ query,
                       const float* __restrict__ b4, float* __restrict__ qterm) {
  int wid = blockIdx.x * 4 + (threadIdx.x >> 6);
  int lane = threadIdx.x & 63;
  int b = wid >> 9, h = wid & 511;
  const float* wr = &w42[h * 1024 + 512];
  const float* q  = &query[b * 512];
  int d = lane * 8;
  f32x4 w0 = *(const f32x4*)&wr[d], w1 = *(const f32x4*)&wr[d + 4];
  f32x4 q0 = *(const f32x4*)&q[d],  q1 = *(const f32x4*)&q[d + 4];
  float s = w0.x*q0.x + w0.y*q0.y + w0.z*q0.z + w0.w*q0.w
          + w1.x*q1.x + w1.y*q1.y + w1.z*q1.z + w1.w*q1.w;
  #pragma unroll
  for (int off = 32; off; off >>= 1) s += __shfl_xor(s, off);
  if (lane == 0) qterm[b * 512 + h] = s + b4[h];
}

// --- B: GEMM + tanh + partial h-reduce.  Block 128h x 128t, 4 waves 64x64.
// XCD-grouped: 4 h-sibling blocks of one (b, t-tile) share keys via L2.
__global__ __launch_bounds__(256, 3) void kGemmE(
    const float* __restrict__ keys, const u16x8* __restrict__ W1swz,
    const float* __restrict__ qterm, const float* __restrict__ w54,
    float* __restrict__ n5p) {
  __shared__ s16x8 Bs[2][512];     // 16 KB: [buf][s*128 + (t^s)]
  __shared__ float red[2][128];

  int p = blockIdx.x;
  int lix = (p & 7) * 512 + (p >> 3);    // XCD chunking
  int hq = lix & 3, tt = (lix >> 2) & 31, b = lix >> 7;
  int h0 = hq * 128, t0 = tt * 128;

  int tid = threadIdx.x, lane = tid & 63, wid = tid >> 6;
  int wh = wid & 1, wt = wid >> 1;       // wave = (64h half, 64t half)
  int lr = lane & 15, lg = lane >> 4;

  // staging: thread covers k-slot s (8 rows), t-cols ta and ta+64
  int s = tid >> 6, ta = tid & 63;
  const float* kp = keys + (size_t)b * DD * TT + (size_t)(s * 8) * TT + t0 + ta;
  int wiA = s * 128 + (ta ^ s), wiB = s * 128 + ((ta + 64) ^ s);
  // A-frags: h = h0 + wh*64 + m*16 + lr, slot lg
  const s16x8* ap = reinterpret_cast<const s16x8*>(W1swz) + lg * 512 + h0 + wh * 64 + lr;
  // B-frag LDS read indices
  int rci[4];
  #pragma unroll
  for (int n = 0; n < 4; ++n) {
    int t = wt * 64 + n * 16 + lr;
    rci[n] = lg * 128 + (t ^ lg);
  }

  f32x4 acc[4][4];
  #pragma unroll
  for (int m = 0; m < 4; ++m)
    #pragma unroll
    for (int n = 0; n < 4; ++n) acc[m][n] = (f32x4){0.f, 0.f, 0.f, 0.f};

  float r[16];
  #pragma unroll
  for (int j = 0; j < 8; ++j) r[j] = kp[(size_t)j * TT];
  #pragma unroll
  for (int j = 0; j < 8; ++j) r[8 + j] = kp[(size_t)j * TT + 64];

  #pragma unroll
  for (int kk = 0; kk < NKK; ++kk) {
    const int cur = kk & 1;
    // A-frags for this step (L2) — issued first (in-order vmcnt discipline)
    s16x8 af[4];
    #pragma unroll
    for (int m = 0; m < 4; ++m) af[m] = ap[kk * 2048 + m * 16];

    // convert r -> two bf16 chunks -> LDS
    union { uint32_t u[4]; s16x8 v; } ca, cb;
    #pragma unroll
    for (int j = 0; j < 4; ++j) {
      ca.u[j] = cvtpk(r[2 * j], r[2 * j + 1]);
      cb.u[j] = cvtpk(r[8 + 2 * j], r[9 + 2 * j]);
    }
    Bs[cur][wiA] = ca.v;
    Bs[cur][wiB] = cb.v;

    // depth-1 prefetch of next step's keys (HBM; issued after af)
    if (kk + 1 < NKK) {
      const float* kp2 = kp + (size_t)(kk + 1) * 32 * TT;
      #pragma unroll
      for (int j = 0; j < 8; ++j) r[j] = kp2[(size_t)j * TT];
      #pragma unroll
      for (int j = 0; j < 8; ++j) r[8 + j] = kp2[(size_t)j * TT + 64];
    }

    asm volatile("s_waitcnt lgkmcnt(0)" ::: "memory");
    __builtin_amdgcn_s_barrier();          // vmcnt NOT drained

    s16x8 bf[4];
    #pragma unroll
    for (int n = 0; n < 4; ++n) bf[n] = Bs[cur][rci[n]];

    #pragma unroll
    for (int m = 0; m < 4; ++m)
      #pragma unroll
      for (int n = 0; n < 4; ++n)
        acc[m][n] = __builtin_amdgcn_mfma_f32_16x16x32_bf16(af[m], bf[n], acc[m][n], 0, 0, 0);
  }

  // epilogue: tanh + w54-weighted reduce over this wave's 64 h
  float part[4] = {0.f, 0.f, 0.f, 0.f};
  #pragma unroll
  for (int m = 0; m < 4; ++m) {
    #pragma unroll
    for (int rr = 0; rr < 4; ++rr) {
      int h = h0 + wh * 64 + m * 16 + lg * 4 + rr;   // C/D: row=(lane>>4)*4+reg
      float qv = qterm[b * HH + h];
      float wvv = w54[h];
      #pragma unroll
      for (int n = 0; n < 4; ++n)
        part[n] += wvv * tanh_fast(acc[m][n][rr] + qv);
    }
  }
  #pragma unroll
  for (int n = 0; n < 4; ++n) {
    part[n] += __shfl_xor(part[n], 16);
    part[n] += __shfl_xor(part[n], 32);
  }
  if (lane < 16) {
    #pragma unroll
    for (int n = 0; n < 4; ++n) red[wh][wt * 64 + n * 16 + lane] = part[n];
  }
  __syncthreads();
  if (tid < 128) {
    float v = red[0][tid] + red[1][tid];
    n5p[((size_t)hq * NB + b) * TT + t0 + tid] = v;   // partial over h-slices
  }
}

// --- C: e[b,t] = exp(sum_hq n5p);  Zinv[b] = 1/sum_t e ---
__global__ void kSoftE(const float* __restrict__ n5p, float* __restrict__ e,
                       float* __restrict__ Zinv) {
  int b = blockIdx.x, tid = threadIdx.x;
  int lane = tid & 63, wid = tid >> 6;
  __shared__ float zsh[4];
  float z = 0.f;
  #pragma unroll
  for (int i = 0; i < 16; ++i) {
    int t = tid + i * 256;
    float v = n5p[(0 * NB + b) * TT + t] + n5p[(1 * NB + b) * TT + t]
            + n5p[(2 * NB + b) * TT + t] + n5p[(3 * NB + b) * TT + t];
    float ev = __expf(v);                 // |n5| <~ 4: no max-sub needed
    e[b * TT + t] = ev;
    z += ev;
  }
  #pragma unroll
  for (int off = 32; off; off >>= 1) z += __shfl_xor(z, off);
  if (lane == 0) zsh[wid] = z;
  __syncthreads();
  if (tid == 0) Zinv[b] = 1.f / (zsh[0] + zsh[1] + zsh[2] + zsh[3]);
}

// --- D: out[b,v] = Zinv[b] * values[b,v,:]·e[b,:] ---
__global__ void kOut(const float* __restrict__ values, const float* __restrict__ e,
                     const float* __restrict__ Zinv, float* __restrict__ out) {
  int blk = blockIdx.x;
  int b = blk >> 7;
  int wid = threadIdx.x >> 6, lane = threadIdx.x & 63;
  int v = (blk & 127) * 4 + wid;
  const float* row = &values[((size_t)b * 512 + v) * TT];
  const float* wv = &e[b * TT];
  float s0 = 0.f, s1 = 0.f, s2 = 0.f, s3 = 0.f;
  #pragma unroll
  for (int i = 0; i < 16; ++i) {
    int t = (i * 64 + lane) * 4;
    f32x4 x = __builtin_nontemporal_load(reinterpret_cast<const f32x4*>(&row[t]));
    f32x4 y = *(const f32x4*)&wv[t];
    float d = x.x * y.x + x.y * y.y + x.z * y.z + x.w * y.w;
    if ((i & 3) == 0) s0 += d; else if ((i & 3) == 1) s1 += d;
    else if ((i & 3) == 2) s2 += d; else s3 += d;
  }
  float s = (s0 + s1) + (s2 + s3);
  #pragma unroll
  for (int off = 32; off; off >>= 1) s += __shfl_xor(s, off);
  if (lane == 0) out[b * 512 + v] = s * Zinv[b];
}

extern "C" void kernel_launch(void* const* d_in, const int* in_sizes, int n_in,
                              void* d_out, int out_size, void* d_ws, size_t ws_size,
                              hipStream_t stream) {
  const float* query  = (const float*)d_in[0];
  const float* keys   = (const float*)d_in[1];
  const float* values = (const float*)d_in[2];
  const float* w42    = (const float*)d_in[3];
  const float* b4     = (const float*)d_in[4];
  const float* w54    = (const float*)d_in[5];
  // d_in[6] (b5) shifts n5 by a constant -> softmax-invariant; unused.
  float* out = (float*)d_out;

  char* ws = (char*)d_ws;
  u16x8* W1swz = (u16x8*)ws;                       // 512 KB
  float* qterm = (float*)(ws + (512 << 10));       // 64 KB
  float* Zinv  = (float*)(ws + (576 << 10));       // 128 B
  float* e     = (float*)(ws + (640 << 10));       // 512 KB [B][T]
  float* n5p   = (float*)(ws + (1152 << 10));      // 2 MB   [4][B][T]

  kConvT <<<128, 256, 0, stream>>>(w42, W1swz);
  kQterm <<<4096, 256, 0, stream>>>(w42, query, b4, qterm);
  kGemmE <<<4096, 256, 0, stream>>>(keys, W1swz, qterm, w54, n5p);
  kSoftE <<<32, 256, 0, stream>>>(n5p, e, Zinv);
  kOut   <<<4096, 256, 0, stream>>>(values, e, Zinv, out);
}